// Round 25
// baseline (159.575 us; speedup 1.0000x reference)
//
#include <hip/hip_runtime.h>
#include <hip/hip_bf16.h>

typedef unsigned short ushort_t;
typedef unsigned int uint_t;
typedef __attribute__((ext_vector_type(8))) short bf16x8;
typedef __attribute__((ext_vector_type(4))) float f32x4;

#define NB 8
#define NS 4096
#define ND 256
#define NH 8
#define NDK 32
#define NBS (NB*NS)                       // 32768 rows
#define NK  (NS+1)                        // 4097 relay keys
#define CH  513                           // relay split-K chunk
#define NCH 8
static const size_t PBUF = (size_t)NB*(NS+1)*ND;   // 8,390,656 floats
static const size_t HSZ  = (size_t)NBS*ND;         // 8,388,608 elems

__device__ __forceinline__ ushort_t f2b(float x){
  union { __hip_bfloat16 b; ushort_t u; } cv; cv.b = __float2bfloat16(x); return cv.u;
}
__device__ __forceinline__ float b2f(ushort_t u){
  union { uint_t u; float f; } cv; cv.u = ((uint_t)u) << 16; return cv.f;
}
__device__ __forceinline__ void gload16(const ushort_t* g, ushort_t* l){
  __builtin_amdgcn_global_load_lds(
      (const __attribute__((address_space(1))) void*)g,
      (__attribute__((address_space(3))) void*)l, 16, 0, 0);
}
__device__ __forceinline__ uint4 packbf16x8(float4 a, float4 b){
  uint4 p;
  p.x = f2b(a.x) | ((uint_t)f2b(a.y)<<16);
  p.y = f2b(a.z) | ((uint_t)f2b(a.w)<<16);
  p.z = f2b(b.x) | ((uint_t)f2b(b.y)<<16);
  p.w = f2b(b.z) | ((uint_t)f2b(b.w)<<16);
  return p;
}

// ---------------- block reduce helpers (blockDim.x == 256) ----------------
__device__ __forceinline__ float bsum256(float v){
  __shared__ float tmp[4];
  #pragma unroll
  for (int o=32;o>0;o>>=1) v += __shfl_down(v,o);
  if ((threadIdx.x & 63)==0) tmp[threadIdx.x>>6] = v;
  __syncthreads();
  float r = tmp[0]+tmp[1]+tmp[2]+tmp[3];
  __syncthreads();
  return r;
}

// ---------------- prep: 6 weight transposes + 5 s-projections ----------------
// grid.x = 136: [0,96) transp; [96,136) sproj
__global__ __launch_bounds__(256) void prep(
    const float* __restrict__ w0, const float* __restrict__ w1, const float* __restrict__ w2,
    const float* __restrict__ w3, const float* __restrict__ w4, const float* __restrict__ w5,
    ushort_t* __restrict__ WtAll,
    const float* __restrict__ s,
    const float* __restrict__ rwq,
    ushort_t* __restrict__ ksb, ushort_t* __restrict__ vsb,
    float* __restrict__ qr, ushort_t* __restrict__ krv)
{
  __shared__ float sh[64*68];
  const int blk = blockIdx.x;
  const int tid = threadIdx.x;
  if (blk < 96){
    const int z = blk >> 4, xy = blk & 15;
    const float* W = (z==0)?w0:(z==1)?w1:(z==2)?w2:(z==3)?w3:(z==4)?w4:w5;
    ushort_t* Wt = WtAll + (size_t)z*65536;
    float (*t)[68] = (float(*)[68])sh;
    const int k0 = (xy>>2)*64, n0 = (xy&3)*64;
    const int tr = tid>>4, tc4 = (tid&15)*4;
    #pragma unroll
    for (int i=0;i<4;i++){
      int r = tr + i*16;
      float4 v = *(const float4*)&W[(size_t)(k0+r)*ND + n0 + tc4];
      t[r][tc4]=v.x; t[r][tc4+1]=v.y; t[r][tc4+2]=v.z; t[r][tc4+3]=v.w;
    }
    __syncthreads();
    #pragma unroll
    for (int i=0;i<4;i++){
      int n = tr + i*16;
      uint_t q0 = f2b(t[tc4+0][n]) | ((uint_t)f2b(t[tc4+1][n])<<16);
      uint_t q1 = f2b(t[tc4+2][n]) | ((uint_t)f2b(t[tc4+3][n])<<16);
      *(uint2*)&Wt[(size_t)(n0+n)*ND + k0 + tc4] = make_uint2(q0,q1);
    }
  } else {
    const int rem = blk - 96;
    const int b = rem & 7, which = rem >> 3;      // 0:ks 1:vs 2:qr 3:krv-K0 4:krv-V0
    const float* W = (which==0)?w1:(which==1)?w2:(which==2)?rwq:(which==3)?w4:w5;
    float* a = sh;
    a[tid] = s[(size_t)b*ND + tid];
    __syncthreads();
    float acc = 0.f;
    #pragma unroll 8
    for (int d=0; d<ND; d++)
      acc = fmaf(a[d], W[(size_t)d*ND + tid], acc);
    switch (which){
      case 0: ksb[(size_t)b*ND + tid] = f2b(acc); break;
      case 1: vsb[(size_t)b*ND + tid] = f2b(acc); break;
      case 2: qr[(size_t)b*ND + tid] = acc; break;
      case 3: krv[(size_t)b*NK*512 + tid] = f2b(acc); break;
      default: krv[(size_t)b*NK*512 + 256 + tid] = f2b(acc); break;
    }
  }
}

// ---------------- fused projection GEMM: A-panel-resident, triple-buffered B, counted vmcnt --
// blk<512: A=h rows, Y=hQKV (6 col-tiles); else A=e, Y=eKV (4 col-tiles).
__global__ __launch_bounds__(512) void gemm_qkve(const float* __restrict__ hA,
    const float* __restrict__ eA, const ushort_t* __restrict__ Wt,
    ushort_t* __restrict__ hQKV, ushort_t* __restrict__ eKV)
{
  __shared__ __align__(16) ushort_t Ap[64][256];      // 32 KB, XOR-swizzled rows
  __shared__ __align__(16) ushort_t Bs[3][128][64];   // 48 KB triple buffer
  const int blk = blockIdx.x;
  const bool isH = blk < 512;
  const float* A = isH ? hA : eA;
  const ushort_t* Wb = isH ? Wt : (Wt + 65536);
  ushort_t* Y = isH ? hQKV : eKV;
  const int ldn  = isH ? 768 : 512;
  const int ncol = isH ? 6 : 4;
  const int row0 = (blk & 511) * 64;
  const int tid = threadIdx.x;
  const int lane = tid & 63;
  const int wave = tid >> 6;            // 0..7
  const int wr  = (wave>>2)*32;         // 0,32
  const int wcw = (wave&3)*32;          // 0,32,64,96 (within 128-col tile)
  const int l15 = lane & 15, lg = lane >> 4;
  const int lr8 = lane >> 3;
  const int ls  = (lane & 7) ^ lr8;

  // ---- stage A panel once: 4 segments of 8 f32 per thread ----
  #pragma unroll
  for (int i=0;i<4;i++){
    int sgi = tid + i*512;
    int r   = sgi >> 5;
    int c8  = (sgi & 31) * 8;
    const float* ga = A + (size_t)(row0 + r)*ND + c8;
    float4 a0 = *(const float4*)ga, a1 = *(const float4*)(ga+4);
    int byte = r*512 + ((c8*2) ^ ((r&7)<<4));
    *(uint4*)((char*)&Ap[0][0] + byte) = packbf16x8(a0,a1);
  }
  asm volatile("s_waitcnt lgkmcnt(0)" ::: "memory");   // Ap writes drained (wave-local)

  const ushort_t* Bbase = Wb + (size_t)(wave*16 + lr8)*ND + ls*8;
  #define STAGEB(ct, kt, bb) do{ \
    const ushort_t* bp = Bbase + (size_t)(ct)*128*ND + (kt)*64; \
    gload16(bp,                &Bs[bb][wave*16][0]); \
    gload16(bp + (size_t)8*ND, &Bs[bb][wave*16+8][0]); \
  }while(0)

  const f32x4 vzero = {0.f,0.f,0.f,0.f};
  f32x4 acc[2][2] = {};
  const int total = ncol*4;
  STAGEB(0, 0, 0);                       // tile 0 in flight (no drain)
  int bcur = 0, bnxt = 1;
  for (int s = 0; s < total; ++s){
    const int kt = s & 3;
    const bool more = (s+1 < total);
    if (more) STAGEB((s+1)>>2, (s+1)&3, bnxt);       // next tile in flight
    if (more) asm volatile("s_waitcnt vmcnt(2)" ::: "memory");   // tile s done, s+1 in flight
    else      asm volatile("s_waitcnt vmcnt(0)" ::: "memory");
    __builtin_amdgcn_s_barrier();                    // all waves' tile-s writes visible
    __builtin_amdgcn_sched_barrier(0);
    #pragma unroll
    for (int ks=0; ks<2; ks++){
      bf16x8 af[2], bfr[2];
      #pragma unroll
      for (int mi=0;mi<2;mi++){
        int ra  = wr + mi*16 + l15;
        int cb2 = kt*128 + ks*64 + lg*16;
        af[mi] = *(const bf16x8*)((const char*)&Ap[0][0] + ra*512 + (cb2 ^ ((ra&7)<<4)));
      }
      #pragma unroll
      for (int ni=0;ni<2;ni++){
        int rb = wcw + ni*16 + l15;
        int cb = (ks<<6) + (lg<<4);
        bfr[ni] = *(const bf16x8*)((const char*)&Bs[bcur][0][0] + rb*128 + (cb ^ ((rb&7)<<4)));
      }
      #pragma unroll
      for (int mi=0;mi<2;mi++)
        #pragma unroll
        for (int ni=0;ni<2;ni++)
          acc[mi][ni] = __builtin_amdgcn_mfma_f32_16x16x32_bf16(af[mi], bfr[ni], acc[mi][ni], 0,0,0);
    }
    bcur = bnxt; bnxt = (bnxt == 2) ? 0 : bnxt + 1;
    if (kt == 3){
      const int col0 = (s >> 2) * 128;
      #pragma unroll
      for (int mi=0;mi<2;mi++)
        #pragma unroll
        for (int r=0;r<4;r++){
          size_t orow = (size_t)(row0 + wr + mi*16 + lg*4 + r);
          #pragma unroll
          for (int ni=0;ni<2;ni++)
            Y[orow*(size_t)ldn + col0 + wcw + ni*16 + l15] = f2b(acc[mi][ni][r]);
        }
      #pragma unroll
      for (int mi=0;mi<2;mi++)
        #pragma unroll
        for (int ni=0;ni<2;ni++)
          acc[mi][ni] = vzero;
    }
  }
  #undef STAGEB
}

// -------- fused: satellite attention + oproj GEMM + residual + LN + relay kr|vr GEMM --------
// Phase 0: sat-attn for 64 rows -> bf16 Ap panel (XOR swizzle).
// Phase 1: x = Ap@Wto + h; LN -> f32 out + Ap overwritten with bf16 h_out.
// Phase 2: kr|vr = Ap @ WtKRV (B direct from L2, no LDS, no barriers). 512 blocks, 512 thr.
__global__ __launch_bounds__(512) void sat_oproj_krv(
    const ushort_t* __restrict__ HQ, const ushort_t* __restrict__ EKV,
    const ushort_t* __restrict__ KS, const ushort_t* __restrict__ VS,
    const ushort_t* __restrict__ Wto, const ushort_t* __restrict__ WtKRV,
    const float* __restrict__ hres,
    const float* __restrict__ g, const float* __restrict__ bta,
    float* __restrict__ outf, ushort_t* __restrict__ krv)
{
  __shared__ __align__(16) ushort_t Ap[64][256];       // 32 KB panel
  __shared__ float rs[64][4], rq[64][4];               // 2 KB
  __shared__ float gl[ND], bl[ND];                     // 2 KB
  const int tid  = threadIdx.x;
  const int row0 = blockIdx.x*64;
  const int lane = tid & 63;
  const int wave = tid >> 6;            // 0..7
  const int wr = (wave>>2)*32;          // 0,32
  const int wc = (wave&3)*64;           // phase1 col base
  const int wcw = (wave&3)*32;          // phase2 col base within 128-tile
  const int l15 = lane & 15, lg = lane >> 4;

  if (tid < ND){ gl[tid] = g[tid]; bl[tid] = bta[tid]; }

  // ---------------- phase 0: satellite attention -> Ap (bf16, XOR swizzle) ----------------
  {
    const int l4 = tid & 3;             // 4-lane k-slice
    const int grp = tid >> 2;           // 0..127
    const int hh = grp & 7;
    const int prow = grp >> 3;          // 0..15
    const float scale = 0.17677669529663687f;
    #pragma unroll
    for (int it=0; it<4; ++it){
      const int pl = it*16 + prow;      // local row 0..63
      const int pos = row0 + pl;
      const int bb = pos >> 12, tt = pos & 4095;
      const int co = hh*NDK + l4*8;
      const size_t rq_ = (size_t)pos*768;
      const size_t re_ = (size_t)pos*512;
      float q[8], k0[8], k1[8], k2[8], k3[8], k4[8];
      {
        bf16x8 v;
        v = *(const bf16x8*)(HQ + rq_ + co);              for(int i=0;i<8;i++) q[i]=b2f((ushort_t)v[i]);
        v = *(const bf16x8*)(HQ + rq_ + 256 + co);        for(int i=0;i<8;i++) k1[i]=b2f((ushort_t)v[i]);
        v = *(const bf16x8*)(EKV + re_ + co);             for(int i=0;i<8;i++) k3[i]=b2f((ushort_t)v[i]);
        v = *(const bf16x8*)(KS + (size_t)bb*ND + co);    for(int i=0;i<8;i++) k4[i]=b2f((ushort_t)v[i]);
        if (tt > 0){ v = *(const bf16x8*)(HQ + rq_ - 768 + 256 + co); for(int i=0;i<8;i++) k0[i]=b2f((ushort_t)v[i]); }
        else        for(int i=0;i<8;i++) k0[i]=0.f;
        if (tt < NS-1){ v = *(const bf16x8*)(HQ + rq_ + 768 + 256 + co); for(int i=0;i<8;i++) k2[i]=b2f((ushort_t)v[i]); }
        else        for(int i=0;i<8;i++) k2[i]=0.f;
      }
      float s0=0.f,s1=0.f,s2=0.f,s3=0.f,s4=0.f;
      #pragma unroll
      for (int i=0;i<8;i++){
        s0 = fmaf(q[i],k0[i],s0); s1 = fmaf(q[i],k1[i],s1); s2 = fmaf(q[i],k2[i],s2);
        s3 = fmaf(q[i],k3[i],s3); s4 = fmaf(q[i],k4[i],s4);
      }
      #pragma unroll
      for (int mm=1; mm<4; mm<<=1){
        s0 += __shfl_xor(s0,mm); s1 += __shfl_xor(s1,mm); s2 += __shfl_xor(s2,mm);
        s3 += __shfl_xor(s3,mm); s4 += __shfl_xor(s4,mm);
      }
      s0*=scale; s1*=scale; s2*=scale; s3*=scale; s4*=scale;
      float m = fmaxf(fmaxf(fmaxf(s0,s1),fmaxf(s2,s3)),s4);
      float p0=expf(s0-m), p1=expf(s1-m), p2=expf(s2-m), p3=expf(s3-m), p4=expf(s4-m);
      float inv = 1.0f/(p0+p1+p2+p3+p4);
      float v0[8], v1[8], v2[8], v3[8], v4[8];
      {
        bf16x8 v;
        v = *(const bf16x8*)(HQ + rq_ + 512 + co);        for(int i=0;i<8;i++) v1[i]=b2f((ushort_t)v[i]);
        v = *(const bf16x8*)(EKV + re_ + 256 + co);       for(int i=0;i<8;i++) v3[i]=b2f((ushort_t)v[i]);
        v = *(const bf16x8*)(VS + (size_t)bb*ND + co);    for(int i=0;i<8;i++) v4[i]=b2f((ushort_t)v[i]);
        if (tt > 0){ v = *(const bf16x8*)(HQ + rq_ - 768 + 512 + co); for(int i=0;i<8;i++) v0[i]=b2f((ushort_t)v[i]); }
        else        for(int i=0;i<8;i++) v0[i]=0.f;
        if (tt < NS-1){ v = *(const bf16x8*)(HQ + rq_ + 768 + 512 + co); for(int i=0;i<8;i++) v2[i]=b2f((ushort_t)v[i]); }
        else        for(int i=0;i<8;i++) v2[i]=0.f;
      }
      float o[8];
      #pragma unroll
      for (int i=0;i<8;i++)
        o[i] = (p0*v0[i] + p1*v1[i] + p2*v2[i] + p3*v3[i] + p4*v4[i]) * inv;
      uint4 pk;
      pk.x = f2b(o[0])|((uint_t)f2b(o[1])<<16);
      pk.y = f2b(o[2])|((uint_t)f2b(o[3])<<16);
      pk.z = f2b(o[4])|((uint_t)f2b(o[5])<<16);
      pk.w = f2b(o[6])|((uint_t)f2b(o[7])<<16);
      int byte = pl*512 + ((co*2) ^ ((pl&7)<<4));
      *(uint4*)((char*)&Ap[0][0] + byte) = pk;
    }
  }
  __syncthreads();                       // Ap (sat-attn output) resident

  // ---------------- phase 1: oproj (A from Ap, B from L2) + residual + LN ----------------
  f32x4 acc[2][4] = {};
  #pragma unroll
  for (int t=0;t<4;t++){
    #pragma unroll
    for (int ks=0; ks<2; ks++){
      bf16x8 af[2], bfr[4];
      #pragma unroll
      for (int mi=0;mi<2;mi++){
        int ra  = wr + mi*16 + l15;
        int cb2 = t*128 + ks*64 + lg*16;
        af[mi] = *(const bf16x8*)((const char*)&Ap[0][0] + ra*512 + (cb2 ^ ((ra&7)<<4)));
      }
      #pragma unroll
      for (int ni=0;ni<4;ni++)
        bfr[ni] = *(const bf16x8*)&Wto[(size_t)(wc + ni*16 + l15)*ND + t*64 + ks*32 + lg*8];
      #pragma unroll
      for (int mi=0;mi<2;mi++)
        #pragma unroll
        for (int ni=0;ni<4;ni++)
          acc[mi][ni] = __builtin_amdgcn_mfma_f32_16x16x32_bf16(af[mi], bfr[ni], acc[mi][ni], 0,0,0);
    }
  }

  // residual add (f32)
  #pragma unroll
  for (int mi=0;mi<2;mi++)
    #pragma unroll
    for (int rr=0;rr<4;rr++){
      size_t rowb = (size_t)(row0 + wr + mi*16 + lg*4 + rr)*ND;
      #pragma unroll
      for (int ni=0;ni<4;ni++)
        acc[mi][ni][rr] += hres[rowb + wc + ni*16 + l15];
    }

  // per-row partials; 16-lane shuffle reduce
  #pragma unroll
  for (int mi=0;mi<2;mi++)
    #pragma unroll
    for (int rr=0;rr<4;rr++){
      float sv = 0.f, qv = 0.f;
      #pragma unroll
      for (int ni=0;ni<4;ni++){ float x = acc[mi][ni][rr]; sv += x; qv += x*x; }
      #pragma unroll
      for (int o=1;o<16;o<<=1){ sv += __shfl_xor(sv,o); qv += __shfl_xor(qv,o); }
      if (l15 == 0){
        int rl = wr + mi*16 + lg*4 + rr;
        rs[rl][wave&3] = sv; rq[rl][wave&3] = qv;
      }
    }
  __syncthreads();                       // all Ap reads done; rs/rq visible

  // LN apply: f32 global write + overwrite Ap with bf16 h_out (XOR swizzle)
  #pragma unroll
  for (int mi=0;mi<2;mi++)
    #pragma unroll
    for (int rr=0;rr<4;rr++){
      int rl = wr + mi*16 + lg*4 + rr;
      float sm = rs[rl][0] + rs[rl][1] + rs[rl][2] + rs[rl][3];
      float sq = rq[rl][0] + rq[rl][1] + rq[rl][2] + rq[rl][3];
      float mu = sm * (1.0f/ND);
      float var = sq * (1.0f/ND) - mu*mu;
      float rstd = rsqrtf(var + 1e-6f);
      size_t rowb = (size_t)(row0 + rl)*ND;
      #pragma unroll
      for (int ni=0;ni<4;ni++){
        int col = wc + ni*16 + l15;
        float yv = (acc[mi][ni][rr] - mu)*rstd*gl[col] + bl[col];
        outf[rowb + col] = yv;
        int byte = rl*512 + ((col*2) ^ ((rl&7)<<4));
        *(ushort_t*)((char*)&Ap[0][0] + byte) = f2b(yv);
      }
    }
  __syncthreads();                       // Ap (h_out) writes visible

  // ---------------- phase 2: kr|vr GEMM over resident panel, B direct from L2 ----------------
  const f32x4 vzero = {0.f,0.f,0.f,0.f};
  f32x4 acc2[2][2] = {};
  #pragma unroll
  for (int ct=0; ct<4; ++ct){
    #pragma unroll
    for (int kt=0; kt<4; ++kt){
      #pragma unroll
      for (int ks=0; ks<2; ks++){
        bf16x8 af[2], bfr[2];
        #pragma unroll
        for (int mi=0;mi<2;mi++){
          int ra  = wr + mi*16 + l15;
          int cb2 = kt*128 + ks*64 + lg*16;
          af[mi] = *(const bf16x8*)((const char*)&Ap[0][0] + ra*512 + (cb2 ^ ((ra&7)<<4)));
        }
        #pragma unroll
        for (int ni=0;ni<2;ni++)
          bfr[ni] = *(const bf16x8*)&WtKRV[(size_t)(ct*128 + wcw + ni*16 + l15)*ND + kt*64 + ks*32 + lg*8];
        #pragma unroll
        for (int mi=0;mi<2;mi++)
          #pragma unroll
          for (int ni=0;ni<2;ni++)
            acc2[mi][ni] = __builtin_amdgcn_mfma_f32_16x16x32_bf16(af[mi], bfr[ni], acc2[mi][ni], 0,0,0);
      }
    }
    const int col0 = ct * 128;
    #pragma unroll
    for (int mi=0;mi<2;mi++)
      #pragma unroll
      for (int r=0;r<4;r++){
        int row = row0 + wr + mi*16 + lg*4 + r;
        size_t orow = (size_t)(row>>12)*NK + 1 + (row&4095);
        #pragma unroll
        for (int ni=0;ni<2;ni++)
          krv[orow*512 + col0 + wcw + ni*16 + l15] = f2b(acc2[mi][ni][r]);
      }
    #pragma unroll
    for (int mi=0;mi<2;mi++)
      #pragma unroll
      for (int ni=0;ni<2;ni++)
        acc2[mi][ni] = vzero;
  }
}

// ---------------- relay attention phase 1: split-K partials over fused krv ----------------
__global__ __launch_bounds__(256) void rel_part(const float* __restrict__ QR,
    const ushort_t* __restrict__ KRV,
    float* __restrict__ pO, float* __restrict__ pM, float* __restrict__ pL)
{
  const int bh = blockIdx.x;
  const int b = bh >> 3, h = bh & 7;
  const int c = blockIdx.y;
  const int k0 = c*CH;
  const int kn = min(NK, k0+CH) - k0;
  const int tid = threadIdx.x;
  __shared__ float sc[CH];
  __shared__ float qs[NDK];
  __shared__ float red[8][NDK];
  __shared__ float tmp[4];
  if (tid < NDK) qs[tid] = QR[(size_t)b*ND + h*NDK + tid];
  __syncthreads();
  const float scale = 0.17677669529663687f;
  for (int kk=tid; kk<kn; kk+=256){
    const ushort_t* kp = KRV + ((size_t)b*NK + k0 + kk)*512 + h*NDK;
    float sdot = 0.f;
    #pragma unroll
    for (int w=0; w<4; w++){
      bf16x8 kv = *(const bf16x8*)(kp + w*8);
      #pragma unroll
      for (int i=0;i<8;i++) sdot = fmaf(qs[w*8+i], b2f((ushort_t)kv[i]), sdot);
    }
    sc[kk] = sdot * scale;
  }
  __syncthreads();
  float lm = -1e30f;
  for (int kk=tid; kk<kn; kk+=256) lm = fmaxf(lm, sc[kk]);
  #pragma unroll
  for (int o=32;o>0;o>>=1) lm = fmaxf(lm, __shfl_down(lm,o));
  if ((tid & 63)==0) tmp[tid>>6] = lm;
  __syncthreads();
  float m = fmaxf(fmaxf(tmp[0],tmp[1]),fmaxf(tmp[2],tmp[3]));
  __syncthreads();
  float ls = 0.f;
  for (int kk=tid; kk<kn; kk+=256){ float p = expf(sc[kk]-m); sc[kk] = p; ls += p; }
  #pragma unroll
  for (int o=32;o>0;o>>=1) ls += __shfl_down(ls,o);
  if ((tid & 63)==0) tmp[tid>>6] = ls;
  __syncthreads();
  float lsum = tmp[0]+tmp[1]+tmp[2]+tmp[3];
  int grp = tid>>5, d = tid&31;
  float acc = 0.f;
  for (int kk=grp; kk<kn; kk+=8)
    acc = fmaf(sc[kk], b2f(KRV[((size_t)b*NK + k0 + kk)*512 + 256 + h*NDK + d]), acc);
  red[grp][d] = acc;
  __syncthreads();
  if (grp == 0){
    float tot = 0.f;
    #pragma unroll
    for (int i=0;i<8;i++) tot += red[i][d];
    pO[((size_t)bh*NCH + c)*NDK + d] = tot;
    if (d == 0){ pM[bh*NCH + c] = m; pL[bh*NCH + c] = lsum; }
  }
}

// ---------------- relay tail: merge partials + wo matvec + LN -> s_out ----------------
__global__ __launch_bounds__(256) void rel_tail(const float* __restrict__ pO,
    const float* __restrict__ pM, const float* __restrict__ pL,
    const float* __restrict__ WO, const float* __restrict__ Sv,
    const float* __restrict__ g, const float* __restrict__ bta,
    float* __restrict__ out)
{
  const int b = blockIdx.x, j = threadIdx.x;
  __shared__ float ol[ND];
  {
    const int h = j >> 5, d = j & 31;
    const int bh = b*NH + h;
    float m = -1e30f;
    #pragma unroll
    for (int c=0;c<NCH;c++) m = fmaxf(m, pM[bh*NCH + c]);
    float o = 0.f, l = 0.f;
    #pragma unroll
    for (int c=0;c<NCH;c++){
      float w = expf(pM[bh*NCH + c] - m);
      o = fmaf(pO[((size_t)bh*NCH + c)*NDK + d], w, o);
      l = fmaf(pL[bh*NCH + c], w, l);
    }
    ol[j] = o / l;
  }
  __syncthreads();
  float x = 0.f;
  for (int d=0; d<ND; d++) x = fmaf(ol[d], WO[(size_t)d*ND + j], x);
  x += Sv[(size_t)b*ND + j];
  float mu = bsum256(x) * (1.0f/ND);
  float dd = x - mu;
  float var = bsum256(dd*dd) * (1.0f/ND);
  out[(size_t)NBS*ND + (size_t)b*ND + j] = dd * rsqrtf(var + 1e-6f) * g[j] + bta[j];
}

extern "C" void kernel_launch(void* const* d_in, const int* in_sizes, int n_in,
                              void* d_out, int out_size, void* d_ws, size_t ws_size,
                              hipStream_t stream)
{
  const float* h      = (const float*)d_in[0];
  const float* e      = (const float*)d_in[1];
  const float* s      = (const float*)d_in[2];
  const float* sat_wq = (const float*)d_in[3];
  const float* sat_wk = (const float*)d_in[4];
  const float* sat_wv = (const float*)d_in[5];
  const float* sat_wo = (const float*)d_in[6];
  const float* sat_g  = (const float*)d_in[7];
  const float* sat_b  = (const float*)d_in[8];
  const float* rel_wq = (const float*)d_in[9];
  const float* rel_wk = (const float*)d_in[10];
  const float* rel_wv = (const float*)d_in[11];
  const float* rel_wo = (const float*)d_in[12];
  const float* rel_g  = (const float*)d_in[13];
  const float* rel_b  = (const float*)d_in[14];
  float* out = (float*)d_out;

  float* ws = (float*)d_ws;
  ushort_t* hQKV = (ushort_t*)ws;                    // [0,1.5P) bf16 [M][768] q|kh|vh
  ushort_t* eKV  = (ushort_t*)(ws + 2*PBUF);         // [2P,3P) bf16 [M][512] ke|ve
  ushort_t* krv  = (ushort_t*)(ws + 4*PBUF);         // [4P,5P) bf16 [B][4097][512] kr|vr
  ushort_t* Wt   = (ushort_t*)(ws + 5*PBUF);         // 6 transposed bf16 weights
  float* smalls  = (float*)(Wt + 6*65536);
  ushort_t* ksb = (ushort_t*)smalls;
  ushort_t* vsb = ksb + 2048;
  float* qr  = smalls + 4096;
  float* pO  = smalls + 8192;
  float* pM  = pO + (size_t)NB*NH*NCH*NDK;
  float* pL  = pM + NB*NH*NCH;

  dim3 gb(256);

  // 1. prep: 6 transposes + 5 s-projections
  prep<<<136, gb, 0, stream>>>(sat_wq, sat_wk, sat_wv, sat_wo, rel_wk, rel_wv, Wt,
                               s, rel_wq, ksb, vsb, qr, krv);

  // 2. fused projections: hQKV + eKV (A-panel-resident, triple-buffer B, counted vmcnt)
  gemm_qkve<<<1024, dim3(512), 0, stream>>>(h, e, Wt, hQKV, eKV);

  // 3. fused satellite attention + oproj + residual + LN + relay kr|vr (B from L2, 36 KB LDS)
  sat_oproj_krv<<<NBS/64, dim3(512), 0, stream>>>(hQKV, eKV, ksb, vsb,
                                                  Wt + 3*65536, Wt + 4*65536,
                                                  h, sat_g, sat_b, out, krv);

  // 4. relay attention partials
  rel_part<<<dim3(NB*NH, NCH), gb, 0, stream>>>(qr, krv, pO, pM, pL);

  // 5. relay merge + output + LN
  rel_tail<<<NB, gb, 0, stream>>>(pO, pM, pL, rel_wo, s, rel_g, rel_b, out);
}

// Round 26
// 144.096 us; speedup vs baseline: 1.1074x; 1.1074x over previous
//
#include <hip/hip_runtime.h>
#include <hip/hip_bf16.h>

typedef unsigned short ushort_t;
typedef unsigned int uint_t;
typedef __attribute__((ext_vector_type(8))) short bf16x8;
typedef __attribute__((ext_vector_type(4))) float f32x4;

#define NB 8
#define NS 4096
#define ND 256
#define NH 8
#define NDK 32
#define NBS (NB*NS)                       // 32768 rows
#define NK  (NS+1)                        // 4097 relay keys
#define CH  513                           // relay split-K chunk
#define NCH 8
static const size_t PBUF = (size_t)NB*(NS+1)*ND;   // 8,390,656 floats
static const size_t HSZ  = (size_t)NBS*ND;         // 8,388,608 elems

__device__ __forceinline__ ushort_t f2b(float x){
  union { __hip_bfloat16 b; ushort_t u; } cv; cv.b = __float2bfloat16(x); return cv.u;
}
__device__ __forceinline__ float b2f(ushort_t u){
  union { uint_t u; float f; } cv; cv.u = ((uint_t)u) << 16; return cv.f;
}
__device__ __forceinline__ void gload16(const ushort_t* g, ushort_t* l){
  __builtin_amdgcn_global_load_lds(
      (const __attribute__((address_space(1))) void*)g,
      (__attribute__((address_space(3))) void*)l, 16, 0, 0);
}
__device__ __forceinline__ uint4 packbf16x8(float4 a, float4 b){
  uint4 p;
  p.x = f2b(a.x) | ((uint_t)f2b(a.y)<<16);
  p.y = f2b(a.z) | ((uint_t)f2b(a.w)<<16);
  p.z = f2b(b.x) | ((uint_t)f2b(b.y)<<16);
  p.w = f2b(b.z) | ((uint_t)f2b(b.w)<<16);
  return p;
}

// ---------------- block reduce helpers (blockDim.x == 256) ----------------
__device__ __forceinline__ float bsum256(float v){
  __shared__ float tmp[4];
  #pragma unroll
  for (int o=32;o>0;o>>=1) v += __shfl_down(v,o);
  if ((threadIdx.x & 63)==0) tmp[threadIdx.x>>6] = v;
  __syncthreads();
  float r = tmp[0]+tmp[1]+tmp[2]+tmp[3];
  __syncthreads();
  return r;
}

// ---------------- prep: 6 weight transposes + 5 s-projections ----------------
// grid.x = 136: [0,96) transp; [96,136) sproj
__global__ __launch_bounds__(256) void prep(
    const float* __restrict__ w0, const float* __restrict__ w1, const float* __restrict__ w2,
    const float* __restrict__ w3, const float* __restrict__ w4, const float* __restrict__ w5,
    ushort_t* __restrict__ WtAll,
    const float* __restrict__ s,
    const float* __restrict__ rwq,
    ushort_t* __restrict__ ksb, ushort_t* __restrict__ vsb,
    float* __restrict__ qr, ushort_t* __restrict__ krv)
{
  __shared__ float sh[64*68];
  const int blk = blockIdx.x;
  const int tid = threadIdx.x;
  if (blk < 96){
    const int z = blk >> 4, xy = blk & 15;
    const float* W = (z==0)?w0:(z==1)?w1:(z==2)?w2:(z==3)?w3:(z==4)?w4:w5;
    ushort_t* Wt = WtAll + (size_t)z*65536;
    float (*t)[68] = (float(*)[68])sh;
    const int k0 = (xy>>2)*64, n0 = (xy&3)*64;
    const int tr = tid>>4, tc4 = (tid&15)*4;
    #pragma unroll
    for (int i=0;i<4;i++){
      int r = tr + i*16;
      float4 v = *(const float4*)&W[(size_t)(k0+r)*ND + n0 + tc4];
      t[r][tc4]=v.x; t[r][tc4+1]=v.y; t[r][tc4+2]=v.z; t[r][tc4+3]=v.w;
    }
    __syncthreads();
    #pragma unroll
    for (int i=0;i<4;i++){
      int n = tr + i*16;
      uint_t q0 = f2b(t[tc4+0][n]) | ((uint_t)f2b(t[tc4+1][n])<<16);
      uint_t q1 = f2b(t[tc4+2][n]) | ((uint_t)f2b(t[tc4+3][n])<<16);
      *(uint2*)&Wt[(size_t)(n0+n)*ND + k0 + tc4] = make_uint2(q0,q1);
    }
  } else {
    const int rem = blk - 96;
    const int b = rem & 7, which = rem >> 3;      // 0:ks 1:vs 2:qr 3:krv-K0 4:krv-V0
    const float* W = (which==0)?w1:(which==1)?w2:(which==2)?rwq:(which==3)?w4:w5;
    float* a = sh;
    a[tid] = s[(size_t)b*ND + tid];
    __syncthreads();
    float acc = 0.f;
    #pragma unroll 8
    for (int d=0; d<ND; d++)
      acc = fmaf(a[d], W[(size_t)d*ND + tid], acc);
    switch (which){
      case 0: ksb[(size_t)b*ND + tid] = f2b(acc); break;
      case 1: vsb[(size_t)b*ND + tid] = f2b(acc); break;
      case 2: qr[(size_t)b*ND + tid] = acc; break;
      case 3: krv[(size_t)b*NK*512 + tid] = f2b(acc); break;
      default: krv[(size_t)b*NK*512 + 256 + tid] = f2b(acc); break;
    }
  }
}

// ---------------- fused projection GEMM: A-panel-resident, triple-buffered B, counted vmcnt --
// blk<512: A=h rows, Y=hQKV (6 col-tiles); else A=e, Y=eKV (4 col-tiles).
__global__ __launch_bounds__(512) void gemm_qkve(const float* __restrict__ hA,
    const float* __restrict__ eA, const ushort_t* __restrict__ Wt,
    ushort_t* __restrict__ hQKV, ushort_t* __restrict__ eKV)
{
  __shared__ __align__(16) ushort_t Ap[64][256];      // 32 KB, XOR-swizzled rows
  __shared__ __align__(16) ushort_t Bs[3][128][64];   // 48 KB triple buffer
  const int blk = blockIdx.x;
  const bool isH = blk < 512;
  const float* A = isH ? hA : eA;
  const ushort_t* Wb = isH ? Wt : (Wt + 65536);
  ushort_t* Y = isH ? hQKV : eKV;
  const int ldn  = isH ? 768 : 512;
  const int ncol = isH ? 6 : 4;
  const int row0 = (blk & 511) * 64;
  const int tid = threadIdx.x;
  const int lane = tid & 63;
  const int wave = tid >> 6;            // 0..7
  const int wr  = (wave>>2)*32;         // 0,32
  const int wcw = (wave&3)*32;          // 0,32,64,96 (within 128-col tile)
  const int l15 = lane & 15, lg = lane >> 4;
  const int lr8 = lane >> 3;
  const int ls  = (lane & 7) ^ lr8;

  // ---- stage A panel once: 4 segments of 8 f32 per thread ----
  #pragma unroll
  for (int i=0;i<4;i++){
    int sgi = tid + i*512;
    int r   = sgi >> 5;
    int c8  = (sgi & 31) * 8;
    const float* ga = A + (size_t)(row0 + r)*ND + c8;
    float4 a0 = *(const float4*)ga, a1 = *(const float4*)(ga+4);
    int byte = r*512 + ((c8*2) ^ ((r&7)<<4));
    *(uint4*)((char*)&Ap[0][0] + byte) = packbf16x8(a0,a1);
  }
  asm volatile("s_waitcnt lgkmcnt(0)" ::: "memory");   // Ap writes drained (wave-local)

  const ushort_t* Bbase = Wb + (size_t)(wave*16 + lr8)*ND + ls*8;
  #define STAGEB(ct, kt, bb) do{ \
    const ushort_t* bp = Bbase + (size_t)(ct)*128*ND + (kt)*64; \
    gload16(bp,                &Bs[bb][wave*16][0]); \
    gload16(bp + (size_t)8*ND, &Bs[bb][wave*16+8][0]); \
  }while(0)

  const f32x4 vzero = {0.f,0.f,0.f,0.f};
  f32x4 acc[2][2] = {};
  const int total = ncol*4;
  STAGEB(0, 0, 0);                       // tile 0 in flight (no drain)
  int bcur = 0, bnxt = 1;
  for (int s = 0; s < total; ++s){
    const int kt = s & 3;
    const bool more = (s+1 < total);
    if (more) STAGEB((s+1)>>2, (s+1)&3, bnxt);       // next tile in flight
    if (more) asm volatile("s_waitcnt vmcnt(2)" ::: "memory");   // tile s done, s+1 in flight
    else      asm volatile("s_waitcnt vmcnt(0)" ::: "memory");
    __builtin_amdgcn_s_barrier();                    // all waves' tile-s writes visible
    __builtin_amdgcn_sched_barrier(0);
    #pragma unroll
    for (int ks=0; ks<2; ks++){
      bf16x8 af[2], bfr[2];
      #pragma unroll
      for (int mi=0;mi<2;mi++){
        int ra  = wr + mi*16 + l15;
        int cb2 = kt*128 + ks*64 + lg*16;
        af[mi] = *(const bf16x8*)((const char*)&Ap[0][0] + ra*512 + (cb2 ^ ((ra&7)<<4)));
      }
      #pragma unroll
      for (int ni=0;ni<2;ni++){
        int rb = wcw + ni*16 + l15;
        int cb = (ks<<6) + (lg<<4);
        bfr[ni] = *(const bf16x8*)((const char*)&Bs[bcur][0][0] + rb*128 + (cb ^ ((rb&7)<<4)));
      }
      #pragma unroll
      for (int mi=0;mi<2;mi++)
        #pragma unroll
        for (int ni=0;ni<2;ni++)
          acc[mi][ni] = __builtin_amdgcn_mfma_f32_16x16x32_bf16(af[mi], bfr[ni], acc[mi][ni], 0,0,0);
    }
    bcur = bnxt; bnxt = (bnxt == 2) ? 0 : bnxt + 1;
    if (kt == 3){
      const int col0 = (s >> 2) * 128;
      #pragma unroll
      for (int mi=0;mi<2;mi++)
        #pragma unroll
        for (int r=0;r<4;r++){
          size_t orow = (size_t)(row0 + wr + mi*16 + lg*4 + r);
          #pragma unroll
          for (int ni=0;ni<2;ni++)
            Y[orow*(size_t)ldn + col0 + wcw + ni*16 + l15] = f2b(acc[mi][ni][r]);
        }
      #pragma unroll
      for (int mi=0;mi<2;mi++)
        #pragma unroll
        for (int ni=0;ni<2;ni++)
          acc[mi][ni] = vzero;
    }
  }
  #undef STAGEB
}

// -------- fused: satellite attention + oproj GEMM + residual + LN + relay kr|vr GEMM --------
// Phase 0: sat-attn for 64 rows -> bf16 Ap panel (XOR swizzle).
// Phase 1: x = Ap@Wto + h; LN -> f32 out + Ap overwritten with bf16 h_out.
// Phase 2: kr|vr = Ap @ WtKRV[512][256], remapped rows. BM=64, 512 blocks, 512 thr.
__global__ __launch_bounds__(512) void sat_oproj_krv(
    const ushort_t* __restrict__ HQ, const ushort_t* __restrict__ EKV,
    const ushort_t* __restrict__ KS, const ushort_t* __restrict__ VS,
    const ushort_t* __restrict__ Wto, const ushort_t* __restrict__ WtKRV,
    const float* __restrict__ hres,
    const float* __restrict__ g, const float* __restrict__ bta,
    float* __restrict__ outf, ushort_t* __restrict__ krv)
{
  __shared__ __align__(16) ushort_t Pool[2][128][64];  // 32 KB (phase 2 B dbuf)
  __shared__ __align__(16) ushort_t Ap[64][256];       // 32 KB panel
  __shared__ float rs[64][4], rq[64][4];               // 2 KB
  __shared__ float gl[ND], bl[ND];                     // 2 KB
  const int tid  = threadIdx.x;
  const int row0 = blockIdx.x*64;
  const int lane = tid & 63;
  const int wave = tid >> 6;            // 0..7
  const int wr = (wave>>2)*32;          // 0,32
  const int wc = (wave&3)*64;           // phase1 col base
  const int wcw = (wave&3)*32;          // phase2 col base within 128-tile
  const int l15 = lane & 15, lg = lane >> 4;
  const int lr8 = lane >> 3;
  const int ls  = (lane & 7) ^ lr8;

  if (tid < ND){ gl[tid] = g[tid]; bl[tid] = bta[tid]; }

  // ---------------- phase 0: satellite attention -> Ap (bf16, XOR swizzle) ----------------
  {
    const int l4 = tid & 3;             // 4-lane k-slice
    const int grp = tid >> 2;           // 0..127
    const int hh = grp & 7;
    const int prow = grp >> 3;          // 0..15
    const float scale = 0.17677669529663687f;
    #pragma unroll
    for (int it=0; it<4; ++it){
      const int pl = it*16 + prow;      // local row 0..63
      const int pos = row0 + pl;
      const int bb = pos >> 12, tt = pos & 4095;
      const int co = hh*NDK + l4*8;
      const size_t rq_ = (size_t)pos*768;
      const size_t re_ = (size_t)pos*512;
      float q[8], k0[8], k1[8], k2[8], k3[8], k4[8];
      {
        bf16x8 v;
        v = *(const bf16x8*)(HQ + rq_ + co);              for(int i=0;i<8;i++) q[i]=b2f((ushort_t)v[i]);
        v = *(const bf16x8*)(HQ + rq_ + 256 + co);        for(int i=0;i<8;i++) k1[i]=b2f((ushort_t)v[i]);
        v = *(const bf16x8*)(EKV + re_ + co);             for(int i=0;i<8;i++) k3[i]=b2f((ushort_t)v[i]);
        v = *(const bf16x8*)(KS + (size_t)bb*ND + co);    for(int i=0;i<8;i++) k4[i]=b2f((ushort_t)v[i]);
        if (tt > 0){ v = *(const bf16x8*)(HQ + rq_ - 768 + 256 + co); for(int i=0;i<8;i++) k0[i]=b2f((ushort_t)v[i]); }
        else        for(int i=0;i<8;i++) k0[i]=0.f;
        if (tt < NS-1){ v = *(const bf16x8*)(HQ + rq_ + 768 + 256 + co); for(int i=0;i<8;i++) k2[i]=b2f((ushort_t)v[i]); }
        else        for(int i=0;i<8;i++) k2[i]=0.f;
      }
      float s0=0.f,s1=0.f,s2=0.f,s3=0.f,s4=0.f;
      #pragma unroll
      for (int i=0;i<8;i++){
        s0 = fmaf(q[i],k0[i],s0); s1 = fmaf(q[i],k1[i],s1); s2 = fmaf(q[i],k2[i],s2);
        s3 = fmaf(q[i],k3[i],s3); s4 = fmaf(q[i],k4[i],s4);
      }
      #pragma unroll
      for (int mm=1; mm<4; mm<<=1){
        s0 += __shfl_xor(s0,mm); s1 += __shfl_xor(s1,mm); s2 += __shfl_xor(s2,mm);
        s3 += __shfl_xor(s3,mm); s4 += __shfl_xor(s4,mm);
      }
      s0*=scale; s1*=scale; s2*=scale; s3*=scale; s4*=scale;
      float m = fmaxf(fmaxf(fmaxf(s0,s1),fmaxf(s2,s3)),s4);
      float p0=expf(s0-m), p1=expf(s1-m), p2=expf(s2-m), p3=expf(s3-m), p4=expf(s4-m);
      float inv = 1.0f/(p0+p1+p2+p3+p4);
      float v0[8], v1[8], v2[8], v3[8], v4[8];
      {
        bf16x8 v;
        v = *(const bf16x8*)(HQ + rq_ + 512 + co);        for(int i=0;i<8;i++) v1[i]=b2f((ushort_t)v[i]);
        v = *(const bf16x8*)(EKV + re_ + 256 + co);       for(int i=0;i<8;i++) v3[i]=b2f((ushort_t)v[i]);
        v = *(const bf16x8*)(VS + (size_t)bb*ND + co);    for(int i=0;i<8;i++) v4[i]=b2f((ushort_t)v[i]);
        if (tt > 0){ v = *(const bf16x8*)(HQ + rq_ - 768 + 512 + co); for(int i=0;i<8;i++) v0[i]=b2f((ushort_t)v[i]); }
        else        for(int i=0;i<8;i++) v0[i]=0.f;
        if (tt < NS-1){ v = *(const bf16x8*)(HQ + rq_ + 768 + 512 + co); for(int i=0;i<8;i++) v2[i]=b2f((ushort_t)v[i]); }
        else        for(int i=0;i<8;i++) v2[i]=0.f;
      }
      float o[8];
      #pragma unroll
      for (int i=0;i<8;i++)
        o[i] = (p0*v0[i] + p1*v1[i] + p2*v2[i] + p3*v3[i] + p4*v4[i]) * inv;
      uint4 pk;
      pk.x = f2b(o[0])|((uint_t)f2b(o[1])<<16);
      pk.y = f2b(o[2])|((uint_t)f2b(o[3])<<16);
      pk.z = f2b(o[4])|((uint_t)f2b(o[5])<<16);
      pk.w = f2b(o[6])|((uint_t)f2b(o[7])<<16);
      int byte = pl*512 + ((co*2) ^ ((pl&7)<<4));
      *(uint4*)((char*)&Ap[0][0] + byte) = pk;
    }
  }
  __syncthreads();                       // Ap (sat-attn output) resident

  // ---------------- phase 1: oproj (A from Ap, B from L2) + residual + LN ----------------
  f32x4 acc[2][4] = {};
  #pragma unroll
  for (int t=0;t<4;t++){
    #pragma unroll
    for (int ks=0; ks<2; ks++){
      bf16x8 af[2], bfr[4];
      #pragma unroll
      for (int mi=0;mi<2;mi++){
        int ra  = wr + mi*16 + l15;
        int cb2 = t*128 + ks*64 + lg*16;
        af[mi] = *(const bf16x8*)((const char*)&Ap[0][0] + ra*512 + (cb2 ^ ((ra&7)<<4)));
      }
      #pragma unroll
      for (int ni=0;ni<4;ni++)
        bfr[ni] = *(const bf16x8*)&Wto[(size_t)(wc + ni*16 + l15)*ND + t*64 + ks*32 + lg*8];
      #pragma unroll
      for (int mi=0;mi<2;mi++)
        #pragma unroll
        for (int ni=0;ni<4;ni++)
          acc[mi][ni] = __builtin_amdgcn_mfma_f32_16x16x32_bf16(af[mi], bfr[ni], acc[mi][ni], 0,0,0);
    }
  }

  // residual add (f32)
  #pragma unroll
  for (int mi=0;mi<2;mi++)
    #pragma unroll
    for (int rr=0;rr<4;rr++){
      size_t rowb = (size_t)(row0 + wr + mi*16 + lg*4 + rr)*ND;
      #pragma unroll
      for (int ni=0;ni<4;ni++)
        acc[mi][ni][rr] += hres[rowb + wc + ni*16 + l15];
    }

  // per-row partials; 16-lane shuffle reduce
  #pragma unroll
  for (int mi=0;mi<2;mi++)
    #pragma unroll
    for (int rr=0;rr<4;rr++){
      float sv = 0.f, qv = 0.f;
      #pragma unroll
      for (int ni=0;ni<4;ni++){ float x = acc[mi][ni][rr]; sv += x; qv += x*x; }
      #pragma unroll
      for (int o=1;o<16;o<<=1){ sv += __shfl_xor(sv,o); qv += __shfl_xor(qv,o); }
      if (l15 == 0){
        int rl = wr + mi*16 + lg*4 + rr;
        rs[rl][wave&3] = sv; rq[rl][wave&3] = qv;
      }
    }
  __syncthreads();                       // all Ap reads done; rs/rq visible

  // LN apply: f32 global write + overwrite Ap with bf16 h_out (XOR swizzle)
  #pragma unroll
  for (int mi=0;mi<2;mi++)
    #pragma unroll
    for (int rr=0;rr<4;rr++){
      int rl = wr + mi*16 + lg*4 + rr;
      float sm = rs[rl][0] + rs[rl][1] + rs[rl][2] + rs[rl][3];
      float sq = rq[rl][0] + rq[rl][1] + rq[rl][2] + rq[rl][3];
      float mu = sm * (1.0f/ND);
      float var = sq * (1.0f/ND) - mu*mu;
      float rstd = rsqrtf(var + 1e-6f);
      size_t rowb = (size_t)(row0 + rl)*ND;
      #pragma unroll
      for (int ni=0;ni<4;ni++){
        int col = wc + ni*16 + l15;
        float yv = (acc[mi][ni][rr] - mu)*rstd*gl[col] + bl[col];
        outf[rowb + col] = yv;
        int byte = rl*512 + ((col*2) ^ ((rl&7)<<4));
        *(ushort_t*)((char*)&Ap[0][0] + byte) = f2b(yv);
      }
    }

  // ---------------- phase 2: kr|vr GEMM over resident panel ----------------
  const ushort_t* Bbase = WtKRV + (size_t)(wave*16 + lr8)*ND + ls*8;
  #define STAGEB(ct, kt, bb) do{ \
    const ushort_t* bp = Bbase + (size_t)(ct)*128*ND + (kt)*64; \
    gload16(bp,                &Pool[bb][wave*16][0]); \
    gload16(bp + (size_t)8*ND, &Pool[bb][wave*16+8][0]); \
  }while(0)

  const f32x4 vzero = {0.f,0.f,0.f,0.f};
  f32x4 acc2[2][2] = {};
  STAGEB(0,0,0);
  __syncthreads();                       // Ap (h_out) writes visible + B tile 0 resident
  int buf = 0;
  for (int s = 0; s < 16; ++s){
    const int kt = s & 3;
    if (s+1 < 16) STAGEB((s+1)>>2, (s+1)&3, buf^1);
    #pragma unroll
    for (int ks=0; ks<2; ks++){
      bf16x8 af[2], bfr[2];
      #pragma unroll
      for (int mi=0;mi<2;mi++){
        int ra  = wr + mi*16 + l15;
        int cb2 = kt*128 + ks*64 + lg*16;
        af[mi] = *(const bf16x8*)((const char*)&Ap[0][0] + ra*512 + (cb2 ^ ((ra&7)<<4)));
      }
      #pragma unroll
      for (int ni=0;ni<2;ni++){
        int rb = wcw + ni*16 + l15;
        int cb = (ks<<6) + (lg<<4);
        bfr[ni] = *(const bf16x8*)((const char*)&Pool[buf][0][0] + rb*128 + (cb ^ ((rb&7)<<4)));
      }
      #pragma unroll
      for (int mi=0;mi<2;mi++)
        #pragma unroll
        for (int ni=0;ni<2;ni++)
          acc2[mi][ni] = __builtin_amdgcn_mfma_f32_16x16x32_bf16(af[mi], bfr[ni], acc2[mi][ni], 0,0,0);
    }
    __syncthreads();
    buf ^= 1;
    if (kt == 3){
      const int col0 = (s >> 2) * 128;
      #pragma unroll
      for (int mi=0;mi<2;mi++)
        #pragma unroll
        for (int r=0;r<4;r++){
          int row = row0 + wr + mi*16 + lg*4 + r;
          size_t orow = (size_t)(row>>12)*NK + 1 + (row&4095);
          #pragma unroll
          for (int ni=0;ni<2;ni++)
            krv[orow*512 + col0 + wcw + ni*16 + l15] = f2b(acc2[mi][ni][r]);
        }
      #pragma unroll
      for (int mi=0;mi<2;mi++)
        #pragma unroll
        for (int ni=0;ni<2;ni++)
          acc2[mi][ni] = vzero;
    }
  }
  #undef STAGEB
}

// ---------------- relay attention phase 1: split-K partials over fused krv ----------------
__global__ __launch_bounds__(256) void rel_part(const float* __restrict__ QR,
    const ushort_t* __restrict__ KRV,
    float* __restrict__ pO, float* __restrict__ pM, float* __restrict__ pL)
{
  const int bh = blockIdx.x;
  const int b = bh >> 3, h = bh & 7;
  const int c = blockIdx.y;
  const int k0 = c*CH;
  const int kn = min(NK, k0+CH) - k0;
  const int tid = threadIdx.x;
  __shared__ float sc[CH];
  __shared__ float qs[NDK];
  __shared__ float red[8][NDK];
  __shared__ float tmp[4];
  if (tid < NDK) qs[tid] = QR[(size_t)b*ND + h*NDK + tid];
  __syncthreads();
  const float scale = 0.17677669529663687f;
  for (int kk=tid; kk<kn; kk+=256){
    const ushort_t* kp = KRV + ((size_t)b*NK + k0 + kk)*512 + h*NDK;
    float sdot = 0.f;
    #pragma unroll
    for (int w=0; w<4; w++){
      bf16x8 kv = *(const bf16x8*)(kp + w*8);
      #pragma unroll
      for (int i=0;i<8;i++) sdot = fmaf(qs[w*8+i], b2f((ushort_t)kv[i]), sdot);
    }
    sc[kk] = sdot * scale;
  }
  __syncthreads();
  float lm = -1e30f;
  for (int kk=tid; kk<kn; kk+=256) lm = fmaxf(lm, sc[kk]);
  #pragma unroll
  for (int o=32;o>0;o>>=1) lm = fmaxf(lm, __shfl_down(lm,o));
  if ((tid & 63)==0) tmp[tid>>6] = lm;
  __syncthreads();
  float m = fmaxf(fmaxf(tmp[0],tmp[1]),fmaxf(tmp[2],tmp[3]));
  __syncthreads();
  float ls = 0.f;
  for (int kk=tid; kk<kn; kk+=256){ float p = expf(sc[kk]-m); sc[kk] = p; ls += p; }
  #pragma unroll
  for (int o=32;o>0;o>>=1) ls += __shfl_down(ls,o);
  if ((tid & 63)==0) tmp[tid>>6] = ls;
  __syncthreads();
  float lsum = tmp[0]+tmp[1]+tmp[2]+tmp[3];
  int grp = tid>>5, d = tid&31;
  float acc = 0.f;
  for (int kk=grp; kk<kn; kk+=8)
    acc = fmaf(sc[kk], b2f(KRV[((size_t)b*NK + k0 + kk)*512 + 256 + h*NDK + d]), acc);
  red[grp][d] = acc;
  __syncthreads();
  if (grp == 0){
    float tot = 0.f;
    #pragma unroll
    for (int i=0;i<8;i++) tot += red[i][d];
    pO[((size_t)bh*NCH + c)*NDK + d] = tot;
    if (d == 0){ pM[bh*NCH + c] = m; pL[bh*NCH + c] = lsum; }
  }
}

// ---------------- relay tail: merge partials + wo matvec + LN -> s_out ----------------
__global__ __launch_bounds__(256) void rel_tail(const float* __restrict__ pO,
    const float* __restrict__ pM, const float* __restrict__ pL,
    const float* __restrict__ WO, const float* __restrict__ Sv,
    const float* __restrict__ g, const float* __restrict__ bta,
    float* __restrict__ out)
{
  const int b = blockIdx.x, j = threadIdx.x;
  __shared__ float ol[ND];
  {
    const int h = j >> 5, d = j & 31;
    const int bh = b*NH + h;
    float m = -1e30f;
    #pragma unroll
    for (int c=0;c<NCH;c++) m = fmaxf(m, pM[bh*NCH + c]);
    float o = 0.f, l = 0.f;
    #pragma unroll
    for (int c=0;c<NCH;c++){
      float w = expf(pM[bh*NCH + c] - m);
      o = fmaf(pO[((size_t)bh*NCH + c)*NDK + d], w, o);
      l = fmaf(pL[bh*NCH + c], w, l);
    }
    ol[j] = o / l;
  }
  __syncthreads();
  float x = 0.f;
  for (int d=0; d<ND; d++) x = fmaf(ol[d], WO[(size_t)d*ND + j], x);
  x += Sv[(size_t)b*ND + j];
  float mu = bsum256(x) * (1.0f/ND);
  float dd = x - mu;
  float var = bsum256(dd*dd) * (1.0f/ND);
  out[(size_t)NBS*ND + (size_t)b*ND + j] = dd * rsqrtf(var + 1e-6f) * g[j] + bta[j];
}

extern "C" void kernel_launch(void* const* d_in, const int* in_sizes, int n_in,
                              void* d_out, int out_size, void* d_ws, size_t ws_size,
                              hipStream_t stream)
{
  const float* h      = (const float*)d_in[0];
  const float* e      = (const float*)d_in[1];
  const float* s      = (const float*)d_in[2];
  const float* sat_wq = (const float*)d_in[3];
  const float* sat_wk = (const float*)d_in[4];
  const float* sat_wv = (const float*)d_in[5];
  const float* sat_wo = (const float*)d_in[6];
  const float* sat_g  = (const float*)d_in[7];
  const float* sat_b  = (const float*)d_in[8];
  const float* rel_wq = (const float*)d_in[9];
  const float* rel_wk = (const float*)d_in[10];
  const float* rel_wv = (const float*)d_in[11];
  const float* rel_wo = (const float*)d_in[12];
  const float* rel_g  = (const float*)d_in[13];
  const float* rel_b  = (const float*)d_in[14];
  float* out = (float*)d_out;

  float* ws = (float*)d_ws;
  ushort_t* hQKV = (ushort_t*)ws;                    // [0,1.5P) bf16 [M][768] q|kh|vh
  ushort_t* eKV  = (ushort_t*)(ws + 2*PBUF);         // [2P,3P) bf16 [M][512] ke|ve
  ushort_t* krv  = (ushort_t*)(ws + 4*PBUF);         // [4P,5P) bf16 [B][4097][512] kr|vr
  ushort_t* Wt   = (ushort_t*)(ws + 5*PBUF);         // 6 transposed bf16 weights
  float* smalls  = (float*)(Wt + 6*65536);
  ushort_t* ksb = (ushort_t*)smalls;
  ushort_t* vsb = ksb + 2048;
  float* qr  = smalls + 4096;
  float* pO  = smalls + 8192;
  float* pM  = pO + (size_t)NB*NH*NCH*NDK;
  float* pL  = pM + NB*NH*NCH;

  dim3 gb(256);

  // 1. prep: 6 transposes + 5 s-projections
  prep<<<136, gb, 0, stream>>>(sat_wq, sat_wk, sat_wv, sat_wo, rel_wk, rel_wv, Wt,
                               s, rel_wq, ksb, vsb, qr, krv);

  // 2. fused projections: hQKV + eKV (A-panel-resident, triple-buffer B, counted vmcnt)
  gemm_qkve<<<1024, dim3(512), 0, stream>>>(h, e, Wt, hQKV, eKV);

  // 3. fused satellite attention + oproj + residual + LN + relay kr|vr
  sat_oproj_krv<<<NBS/64, dim3(512), 0, stream>>>(hQKV, eKV, ksb, vsb,
                                                  Wt + 3*65536, Wt + 4*65536,
                                                  h, sat_g, sat_b, out, krv);

  // 4. relay attention partials
  rel_part<<<dim3(NB*NH, NCH), gb, 0, stream>>>(qr, krv, pO, pM, pL);

  // 5. relay merge + output + LN
  rel_tail<<<NB, gb, 0, stream>>>(pO, pM, pL, rel_wo, s, rel_g, rel_b, out);
}